// Round 2
// baseline (306.261 us; speedup 1.0000x reference)
//
#include <hip/hip_runtime.h>
#include <hip/hip_bf16.h>

// Problem constants (from reference setup_inputs / module constants)
constexpr int   B  = 2;
constexpr int   C  = 256;
constexpr int   H  = 200;
constexpr int   W  = 272;
constexpr int   PH = 14;
constexpr int   PW = 14;
constexpr int   SR = 2;            // sampling ratio
constexpr float SPATIAL_SCALE = 0.25f;
constexpr float ROI_SCALE     = 1.2f;
// SPATIAL_SHIFT = 0.0, HALF_PART = 0 -> no-ops, omitted

__global__ __launch_bounds__(256) void roi_mask_align_kernel(
        const float* __restrict__ feat,   // (B,C,H,W)
        const float* __restrict__ rois,   // (K,5): b,x1,y1,x2,y2
        float* __restrict__ out,          // (K,C,PH,PW)
        int total) {
    int n = blockIdx.x * blockDim.x + threadIdx.x;
    if (n >= total) return;

    int pw = n % PW;
    int ph = (n / PW) % PH;
    int c  = (n / (PW * PH)) % C;
    int k  = n / (PW * PH * C);

    const float* r = rois + (size_t)k * 5;
    int   b  = (int)r[0];
    float x1 = r[1], y1 = r[2], x2 = r[3], y2 = r[4];

    float cx = (x1 + x2) * 0.5f;
    float cy = (y1 + y2) * 0.5f;
    float w  = (x2 - x1) * ROI_SCALE;
    float h  = (y2 - y1) * ROI_SCALE;
    x1 = (cx - 0.5f * w) * SPATIAL_SCALE;
    x2 = (cx + 0.5f * w) * SPATIAL_SCALE;
    y1 = (cy - 0.5f * h) * SPATIAL_SCALE;
    y2 = (cy + 0.5f * h) * SPATIAL_SCALE;

    float roi_w = fmaxf(x2 - x1, 1.0f);
    float roi_h = fmaxf(y2 - y1, 1.0f);
    float bin_h = roi_h * (1.0f / PH);
    float bin_w = roi_w * (1.0f / PW);

    const float* fplane = feat + ((size_t)b * C + c) * (size_t)(H * W);

    float acc = 0.0f;
    #pragma unroll
    for (int iy = 0; iy < SR; ++iy) {
        float yy = y1 + ((float)ph + ((float)iy + 0.5f) / (float)SR) * bin_h;
        // valid predicate folded into weights (branchless); clamped coords are
        // always in-bounds so the 4 loads are safe either way.
        float vy = ((yy > -1.0f) && (yy < (float)H)) ? 1.0f : 0.0f;
        float yc = fminf(fmaxf(yy, 0.0f), (float)(H - 1));
        int   y0 = (int)floorf(yc);
        int   y1i = min(y0 + 1, H - 1);
        float ly = yc - (float)y0;
        float hy = 1.0f - ly;
        #pragma unroll
        for (int ix = 0; ix < SR; ++ix) {
            float xx = x1 + ((float)pw + ((float)ix + 0.5f) / (float)SR) * bin_w;
            float vxy = ((xx > -1.0f) && (xx < (float)W)) ? vy : 0.0f;
            float xc = fminf(fmaxf(xx, 0.0f), (float)(W - 1));
            int   x0 = (int)floorf(xc);
            int   x1i = min(x0 + 1, W - 1);
            float lx = xc - (float)x0;
            float hx = 1.0f - lx;
            const float* row0 = fplane + (size_t)y0  * W;
            const float* row1 = fplane + (size_t)y1i * W;
            float v00 = row0[x0];
            float v01 = row0[x1i];
            float v10 = row1[x0];
            float v11 = row1[x1i];
            float bil = hy * hx * v00 + hy * lx * v01 + ly * hx * v10 + ly * lx * v11;
            acc += vxy * bil;
        }
    }
    out[n] = acc * (1.0f / (SR * SR));
}

extern "C" void kernel_launch(void* const* d_in, const int* in_sizes, int n_in,
                              void* d_out, int out_size, void* d_ws, size_t ws_size,
                              hipStream_t stream) {
    const float* feat = (const float*)d_in[0];
    const float* rois = (const float*)d_in[1];
    float* out = (float*)d_out;

    int K = in_sizes[1] / 5;          // 256
    int total = K * C * PH * PW;      // == out_size

    int block = 256;
    int grid  = (total + block - 1) / block;
    roi_mask_align_kernel<<<grid, block, 0, stream>>>(feat, rois, out, total);
}